// Round 11
// baseline (465.748 us; speedup 1.0000x reference)
//
#include <hip/hip_runtime.h>
#include <hip/hip_bf16.h>
#include <cstdint>
#include <cstddef>

// ---------------- problem constants ----------------
#define TOKENS   8192          // B*S
#define HID      2048
#define LAT      512
#define LAT2     1024
#define GCOLS    2048          // 4 gates * LAT (packed col = 4*l + g)
#define STEPS    8
#define DEC_ELEMS (TOKENS*HID)

typedef __attribute__((ext_vector_type(8))) __bf16 bf16x8;
typedef __attribute__((ext_vector_type(4))) float  f32x4;

// ---------------- helpers ----------------
__device__ __forceinline__ unsigned short f32_to_bf16_rne(float f) {
  unsigned int u = __float_as_uint(f);
  unsigned int r = (u + 0x7FFFu + ((u >> 16) & 1u)) >> 16;
  return (unsigned short)r;
}
__device__ __forceinline__ float bf16_to_f32(unsigned short u) {
  return __uint_as_float(((unsigned int)u) << 16);
}

__device__ __forceinline__ float sigmoidf_(float x) {
  if (x >= 0.f) { float e = __expf(-x); return 1.f / (1.f + e); }
  float e = __expf(x); return e / (1.f + e);
}
__device__ __forceinline__ float tanhf_(float x) {
  float ax = fabsf(x);
  float e  = __expf(-2.f * ax);
  float t  = (1.f - e) / (1.f + e);
  return copysignf(t, x);
}

__device__ __forceinline__ void gl_lds16(const void* g, void* l) {
  __builtin_amdgcn_global_load_lds(
      (const __attribute__((address_space(1))) void*)g,
      (__attribute__((address_space(3))) void*)l, 16, 0, 0);
}

#define WAIT_LGKM0() asm volatile("s_waitcnt lgkmcnt(0)" ::: "memory")
#define WAIT_VM(n)   asm volatile("s_waitcnt vmcnt(" #n ")" ::: "memory")

// ---------------- single merged prep kernel ----------------
// blocks [0,2048): Wg gate-pack (one block per packed row gc) + biasg.
// blocks [2048,3072): fp32->bf16 casts for hs, We1, We2, Wd1, Wd2.
__global__ __launch_bounds__(256)
void k_prep_all(const float* __restrict__ hs,
                const float* __restrict__ We1, const float* __restrict__ We2,
                const float* __restrict__ Wd1, const float* __restrict__ Wd2,
                const float* __restrict__ wih, const float* __restrict__ whh,
                const float* __restrict__ bih, const float* __restrict__ bhh,
                unsigned short* __restrict__ A0,
                unsigned short* __restrict__ We1b, unsigned short* __restrict__ We2b,
                unsigned short* __restrict__ Wd1b, unsigned short* __restrict__ Wd2b,
                unsigned short* __restrict__ Wg,   float* __restrict__ biasg) {
  const int bid = blockIdx.x;
  if (bid < 2048) {
    // pack: row gc = 4*l + g; g in {0: r-sum, 1: z-sum, 2: i_n, 3: h_n}
    int gc = bid;
    int l  = gc >> 2;
    int g  = gc & 3;
    int row = (g == 0) ? l : (g == 1) ? (512 + l) : (1024 + l);
    const float4* wa = (const float4*)(wih + (size_t)row * LAT);
    const float4* wb = (const float4*)(whh + (size_t)row * LAT);
    for (int c4 = threadIdx.x; c4 < 128; c4 += blockDim.x) {
      float4 a = wa[c4], b = wb[c4], v;
      if (g <= 1)      { v.x = a.x + b.x; v.y = a.y + b.y; v.z = a.z + b.z; v.w = a.w + b.w; }
      else if (g == 2) v = a;
      else             v = b;
      ushort4 o;
      o.x = f32_to_bf16_rne(v.x);
      o.y = f32_to_bf16_rne(v.y);
      o.z = f32_to_bf16_rne(v.z);
      o.w = f32_to_bf16_rne(v.w);
      ((ushort4*)(Wg + (size_t)gc * LAT))[c4] = o;
    }
    if (threadIdx.x == 0) {
      biasg[gc] = (g <= 1) ? (bih[row] + bhh[row]) : (g == 2 ? bih[row] : bhh[row]);
    }
  } else {
    // casts: hs 4194304 f4 | We1 524288 | We2 131072 | Wd1 131072 | Wd2 524288
    const int total = 5505024;
    int i = (bid - 2048) * 256 + threadIdx.x;
    const int stride = 1024 * 256;
    for (; i < total; i += stride) {
      const float* s; unsigned short* d; int j;
      if (i < 4194304)      { s = hs;  d = A0;   j = i; }
      else if (i < 4718592) { s = We1; d = We1b; j = i - 4194304; }
      else if (i < 4849664) { s = We2; d = We2b; j = i - 4718592; }
      else if (i < 4980736) { s = Wd1; d = Wd1b; j = i - 4849664; }
      else                  { s = Wd2; d = Wd2b; j = i - 4980736; }
      float4 v = ((const float4*)s)[j];
      ushort4 o;
      o.x = f32_to_bf16_rne(v.x);
      o.y = f32_to_bf16_rne(v.y);
      o.z = f32_to_bf16_rne(v.z);
      o.w = f32_to_bf16_rne(v.w);
      ((ushort4*)d)[j] = o;
    }
  }
}

// =======================================================================
// 256x256 8-phase pipeline pieces (T2 swizzle + T3/T4 counted vmcnt + T5)
// =======================================================================

#define LOAD_A(buf, mh) { \
  const int baseA = (buf)*65536 + wm*16384; \
  _Pragma("unroll") for (int m4 = 0; m4 < 4; ++m4) \
  _Pragma("unroll") for (int kki = 0; kki < 2; ++kki) { \
    int rl = (mh)*64 + m4*16 + lr; \
    int off = (rl*128 + kki*64 + lq*16) ^ ((rl & 7) << 4); \
    aR[mh][m4][kki] = *(const bf16x8*)(lds_ + baseA + off); } }

#define LOAD_B(buf, nh) { \
  const int baseB = (buf)*65536 + 32768 + (wn >> 1)*16384; \
  _Pragma("unroll") for (int n2 = 0; n2 < 2; ++n2) \
  _Pragma("unroll") for (int kki = 0; kki < 2; ++kki) { \
    int rl = (wn & 1)*64 + ((nh)*2 + n2)*16 + lr; \
    int off = (rl*128 + kki*64 + lq*16) ^ ((rl & 7) << 4); \
    bR[nh][n2][kki] = *(const bf16x8*)(lds_ + baseB + off); } }

#define STAGE_A(buf, half, kt) { \
  const unsigned short* gp = A + (size_t)(m0 + (half)*128 + rr8)*K + (size_t)(kt)*64 + cc8; \
  char* dp = lds_ + (buf)*65536 + (half)*16384 + (wv << 10); \
  gl_lds16(gp, dp); \
  gl_lds16(gp + (size_t)64*K, dp + 8192); }

#define STAGE_B(buf, half, kt) { \
  const unsigned short* gp = W + (size_t)(n0 + (half)*128 + rr8)*K + (size_t)(kt)*64 + cc8; \
  char* dp = lds_ + (buf)*65536 + 32768 + (half)*16384 + (wv << 10); \
  gl_lds16(gp, dp); \
  gl_lds16(gp + (size_t)64*K, dp + 8192); }

#define MFMAQ(mh, nh) \
  _Pragma("unroll") for (int kki = 0; kki < 2; ++kki) \
  _Pragma("unroll") for (int n2 = 0; n2 < 2; ++n2) \
  _Pragma("unroll") for (int m4 = 0; m4 < 4; ++m4) \
    acc[(mh)*4 + m4][(nh)*2 + n2] = __builtin_amdgcn_mfma_f32_16x16x32_bf16( \
        aR[mh][m4][kki], bR[nh][n2][kki], acc[(mh)*4 + m4][(nh)*2 + n2], 0, 0, 0);

#define PH_CORE(mh, nh) \
  __builtin_amdgcn_s_barrier(); \
  WAIT_LGKM0(); \
  __builtin_amdgcn_sched_barrier(0); \
  __builtin_amdgcn_s_setprio(1); \
  MFMAQ(mh, nh); \
  __builtin_amdgcn_sched_barrier(0); \
  __builtin_amdgcn_s_setprio(0);

#define PH_BAR() __builtin_amdgcn_s_barrier();

// K-loop ROLLED (#pragma unroll 1): one body copy in I$ (R5 lesson).
#define KLOOP_MAIN(tlim) \
  _Pragma("unroll 1") \
  for (int t = 0; t < (tlim); ++t) { \
    const int kt1 = 2 * t + 1, kt2 = 2 * t + 2, kt3 = 2 * t + 3; \
    LOAD_A(0, 0) LOAD_B(0, 0) \
    STAGE_A(1, 0, kt1) \
    PH_CORE(0, 0) PH_BAR() \
    LOAD_B(0, 1) \
    STAGE_A(1, 1, kt1) \
    PH_CORE(0, 1) PH_BAR() \
    LOAD_A(0, 1) \
    STAGE_B(0, 0, kt2) \
    PH_CORE(1, 1) PH_BAR() \
    STAGE_B(0, 1, kt2) \
    PH_CORE(1, 0) \
    WAIT_VM(4); \
    PH_BAR() \
    LOAD_A(1, 0) LOAD_B(1, 0) \
    STAGE_A(0, 0, kt2) \
    PH_CORE(0, 0) PH_BAR() \
    LOAD_B(1, 1) \
    STAGE_A(0, 1, kt2) \
    PH_CORE(0, 1) PH_BAR() \
    LOAD_A(1, 1) \
    STAGE_B(1, 0, kt3) \
    PH_CORE(1, 1) PH_BAR() \
    STAGE_B(1, 1, kt3) \
    PH_CORE(1, 0) \
    WAIT_VM(4); \
    PH_BAR() \
  }

#define KLOOP_LAST(ktL) { \
    LOAD_A(0, 0) LOAD_B(0, 0) \
    STAGE_A(1, 0, (ktL)) \
    PH_CORE(0, 0) PH_BAR() \
    LOAD_B(0, 1) \
    STAGE_A(1, 1, (ktL)) \
    PH_CORE(0, 1) PH_BAR() \
    LOAD_A(0, 1) \
    PH_CORE(1, 1) PH_BAR() \
    PH_CORE(1, 0) \
    WAIT_VM(0); \
    PH_BAR() \
    LOAD_A(1, 0) LOAD_B(1, 0) \
    PH_CORE(0, 0) PH_BAR() \
    LOAD_B(1, 1) \
    PH_CORE(0, 1) PH_BAR() \
    LOAD_A(1, 1) \
    PH_CORE(1, 1) PH_BAR() \
    PH_CORE(1, 0) \
    PH_BAR() \
  }

// ---------------- unified 256^2 GEMM kernel ----------------
// EPI 0: outB = bf16(relu(acc+bias)) | EPI 1: outB = bf16(acc+bias)
// EPI 2: outF = acc+bias (fp32)
template <int EPI>
__global__ __launch_bounds__(512, 2)
void gemm256(const unsigned short* __restrict__ A,   // [M x K] bf16 bits
             const unsigned short* __restrict__ W,   // [N x K] bf16 bits
             const float* __restrict__ bias,         // [N]
             int K, int N, int Ntiles,
             unsigned short* __restrict__ outB,
             float* __restrict__ outF) {
  __shared__ __align__(16) char lds_[131072];

  const int tid  = threadIdx.x;
  const int lane = tid & 63;
  const int wv   = tid >> 6;
  const int wm   = wv >> 2;
  const int wn   = wv & 3;
  const int lr   = lane & 15;
  const int lq   = lane >> 4;
  const int rr8 = (wv << 3) + (lane >> 3);
  const int cc8 = ((lane & 7) ^ (lane >> 3)) << 3;

  const int nwg = gridDim.x;
  const int wg  = blockIdx.x;
  const int swz = (wg & 7) * (nwg >> 3) + (wg >> 3);   // bijective: nwg % 8 == 0
  const int tm  = swz / Ntiles;
  const int tn  = swz % Ntiles;
  const int m0  = tm * 256;
  const int n0  = tn * 256;

  f32x4 acc[8][4];
#pragma unroll
  for (int i = 0; i < 8; ++i)
#pragma unroll
    for (int j = 0; j < 4; ++j) acc[i][j] = (f32x4){0.f, 0.f, 0.f, 0.f};

  bf16x8 aR[2][4][2];
  bf16x8 bR[2][2][2];

  const int nIt = K >> 7;

  STAGE_B(0, 0, 0) STAGE_B(0, 1, 0) STAGE_A(0, 0, 0) STAGE_A(0, 1, 0)
  STAGE_B(1, 0, 1) STAGE_B(1, 1, 1)
  WAIT_VM(4);
  __builtin_amdgcn_s_barrier();

  KLOOP_MAIN(nIt - 1)
  KLOOP_LAST(2 * nIt - 1)

  float bj[4];
#pragma unroll
  for (int nf = 0; nf < 4; ++nf) bj[nf] = bias[n0 + wn * 64 + nf * 16 + lr];
#pragma unroll
  for (int mf = 0; mf < 8; ++mf) {
#pragma unroll
    for (int ii = 0; ii < 4; ++ii) {
      int row = m0 + wm * 128 + mf * 16 + lq * 4 + ii;
#pragma unroll
      for (int nf = 0; nf < 4; ++nf) {
        int col = n0 + wn * 64 + nf * 16 + lr;
        float v = acc[mf][nf][ii] + bj[nf];
        if constexpr (EPI == 0) {
          outB[(size_t)row * N + col] = f32_to_bf16_rne(fmaxf(v, 0.f));
        } else if constexpr (EPI == 1) {
          outB[(size_t)row * N + col] = f32_to_bf16_rne(v);
        } else {
          outF[(size_t)row * N + col] = v;
        }
      }
    }
  }
}

// ---------------- GRU step kernel (one launch per step) ----------------
__global__ __launch_bounds__(512, 2)
void gemm256_gru(const unsigned short* __restrict__ A,   // h_in bf16 [TOKENS x LAT]
                 const unsigned short* __restrict__ W,   // Wg [GCOLS x LAT]
                 const float* __restrict__ bias,         // biasg
                 int K, int N, int Ntiles,
                 unsigned short* __restrict__ outB,      // h_out bf16
                 const unsigned short* __restrict__ hInB,
                 float* __restrict__ traj,
                 int step) {
  __shared__ __align__(16) char lds_[131072];

  const int tid  = threadIdx.x;
  const int lane = tid & 63;
  const int wv   = tid >> 6;
  const int wm   = wv >> 2;
  const int wn   = wv & 3;
  const int lr   = lane & 15;
  const int lq   = lane >> 4;
  const int rr8 = (wv << 3) + (lane >> 3);
  const int cc8 = ((lane & 7) ^ (lane >> 3)) << 3;

  const int nwg = gridDim.x;
  const int wg  = blockIdx.x;
  const int swz = (wg & 7) * (nwg >> 3) + (wg >> 3);
  const int tm  = swz / Ntiles;
  const int tn  = swz % Ntiles;
  const int m0  = tm * 256;
  const int n0  = tn * 256;

  f32x4 acc[8][4];
#pragma unroll
  for (int i = 0; i < 8; ++i)
#pragma unroll
    for (int j = 0; j < 4; ++j) acc[i][j] = (f32x4){0.f, 0.f, 0.f, 0.f};

  bf16x8 aR[2][4][2];
  bf16x8 bR[2][2][2];

  const int nIt = K >> 7;

  STAGE_B(0, 0, 0) STAGE_B(0, 1, 0) STAGE_A(0, 0, 0) STAGE_A(0, 1, 0)
  STAGE_B(1, 0, 1) STAGE_B(1, 1, 1)
  WAIT_VM(4);
  __builtin_amdgcn_s_barrier();

  KLOOP_MAIN(nIt - 1)
  KLOOP_LAST(2 * nIt - 1)

  float bj[4];
#pragma unroll
  for (int nf = 0; nf < 4; ++nf) bj[nf] = bias[n0 + wn * 64 + nf * 16 + lr];

  // GRU gate epilogue: wave tile = 128 tokens x 64 gate cols = 16 latents
  float* scr = (float*)lds_ + wv * 1088;      // 16 x 68 floats per wave
  const int latBase = tn * 64 + wn * 16;
  const int la = lane & 15;
  const int th = lane >> 4;
#pragma unroll
  for (int mf = 0; mf < 8; ++mf) {
    WAIT_LGKM0();
#pragma unroll
    for (int nf = 0; nf < 4; ++nf)
#pragma unroll
      for (int ii = 0; ii < 4; ++ii)
        scr[(lq * 4 + ii) * 68 + nf * 16 + lr] = acc[mf][nf][ii] + bj[nf];
    WAIT_LGKM0();
#pragma unroll
    for (int tb = 0; tb < 4; ++tb) {
      int tt = th * 4 + tb;
      int token = m0 + wm * 128 + mf * 16 + tt;
      f32x4 g = *(const f32x4*)(scr + tt * 68 + la * 4);  // [r̂, ẑ, i_n, h_n]
      int latc = latBase + la;
      float h  = bf16_to_f32(hInB[(size_t)token * LAT + latc]);
      float r  = sigmoidf_(g.x);
      float z  = sigmoidf_(g.y);
      float n  = tanhf_(g.z + r * g.w);
      float hn = (1.f - z) * n + z * h;
      outB[(size_t)token * LAT + latc] = f32_to_bf16_rne(hn);
      traj[(size_t)token * (STEPS * LAT) + step * LAT + latc] = hn;
    }
  }
}

// ---------------- launcher ----------------
extern "C" void kernel_launch(void* const* d_in, const int* in_sizes, int n_in,
                              void* d_out, int out_size, void* d_ws, size_t ws_size,
                              hipStream_t stream) {
  const float* hs  = (const float*)d_in[0];
  const float* We1 = (const float*)d_in[2];
  const float* be1 = (const float*)d_in[3];
  const float* We2 = (const float*)d_in[4];
  const float* be2 = (const float*)d_in[5];
  const float* Wd1 = (const float*)d_in[6];
  const float* bd1 = (const float*)d_in[7];
  const float* Wd2 = (const float*)d_in[8];
  const float* bd2 = (const float*)d_in[9];
  const float* wih = (const float*)d_in[10];
  const float* whh = (const float*)d_in[11];
  const float* bih = (const float*)d_in[12];
  const float* bhh = (const float*)d_in[13];

  char* ws = (char*)d_ws;
  unsigned short* A0    = (unsigned short*)(ws + 0);          // 33,554,432 B
  unsigned short* We1b  = (unsigned short*)(ws + 33554432);   //  4,194,304
  unsigned short* We2b  = (unsigned short*)(ws + 37748736);   //  1,048,576
  unsigned short* Wd1b  = (unsigned short*)(ws + 38797312);   //  1,048,576
  unsigned short* Wd2b  = (unsigned short*)(ws + 39845888);   //  4,194,304
  unsigned short* Wg    = (unsigned short*)(ws + 44040192);   //  2,097,152
  float*          biasg = (float*)         (ws + 46137344);   //      8,192
  unsigned short* X1    = (unsigned short*)(ws + 46145536);   // 16,777,216
  unsigned short* Lb0   = (unsigned short*)(ws + 62922752);   //  8,388,608
  unsigned short* Lb1   = (unsigned short*)(ws + 71311360);   //  8,388,608
  unsigned short* X2    = A0;                                 // A0 dead after E1

  float* dec  = (float*)d_out;
  float* traj = (float*)d_out + DEC_ELEMS;

  // single prep dispatch: all casts + GRU pack
  k_prep_all<<<3072, 256, 0, stream>>>(hs, We1, We2, Wd1, Wd2,
                                       wih, whh, bih, bhh,
                                       A0, We1b, We2b, Wd1b, Wd2b, Wg, biasg);

  // encode (all on the 8-phase 256^2 engine)
  gemm256<0><<<128, 512, 0, stream>>>(A0, We1b, be1, HID, LAT2, 4, X1, nullptr);
  gemm256<1><<<64,  512, 0, stream>>>(X1, We2b, be2, LAT2, LAT, 2, Lb0, nullptr);
  // 8 GRU steps (double-buffered bf16 latent)
  for (int s = 0; s < STEPS; ++s) {
    const unsigned short* lbi = (s & 1) ? Lb1 : Lb0;
    unsigned short*       lbo = (s & 1) ? Lb0 : Lb1;
    gemm256_gru<<<256, 512, 0, stream>>>(lbi, Wg, biasg, LAT, GCOLS, 8,
                                         lbo, lbi, traj, s);
  }
  // decode
  gemm256<0><<<128, 512, 0, stream>>>(Lb0, Wd1b, bd1, LAT, LAT2, 4, X2, nullptr);
  gemm256<2><<<256, 512, 0, stream>>>(X2, Wd2b, bd2, LAT2, HID, 8, nullptr, dec);
}